// Round 7
// baseline (1858.583 us; speedup 1.0000x reference)
//
#include <hip/hip_runtime.h>
#include <stdint.h>

// Problem constants
constexpr int B_ = 8, N_ = 4096, E_ = 2048, C_ = 128;
constexpr int KT = 32;     // K per MFMA step
constexpr int MT = 64;     // M rows per block (4 x 16-row groups)
constexpr int NJW = 2;     // col-tiles per wave (8 tiles / 4 waves) -- N-split

typedef short bf16x8 __attribute__((ext_vector_type(8)));
typedef float f32x4  __attribute__((ext_vector_type(4)));
typedef unsigned int u32x4 __attribute__((ext_vector_type(4)));

__device__ inline uint16_t bf16_rne(float f) {
    uint32_t u = __builtin_bit_cast(uint32_t, f);
    return (uint16_t)((u + 0x7FFFu + ((u >> 16) & 1u)) >> 16);
}

constexpr size_t HT_E  = (size_t)B_ * (N_ / 32) * E_;  // 2M dwords = 8 MB
constexpr size_t WT_E  = (size_t)C_ * C_;              // 16384 bf16
constexpr size_t EBF_E = (size_t)B_ * C_ * E_;         // 2M bf16 = 4 MB
constexpr size_t RS_E  = (size_t)B_ * E_;              // 16K floats
constexpr size_t RD_E  = (size_t)B_ * N_;              // 32K floats

// ---------------------------------------------------------------------------
// pack: H (fp32 0/1) -> HT[b][n/32][e]. REP>1 = rocprof surfacing (idempotent).
// ---------------------------------------------------------------------------
template <int REP>
__global__ void pack_kernel(const float* __restrict__ H, uint32_t* __restrict__ HT) {
    const int t  = threadIdx.x;
    const int eg = blockIdx.x & 7;
    const int ng = (blockIdx.x >> 3) & 127;
    const int b  = blockIdx.x >> 10;
    const int e  = eg * 256 + t;
    const float* hp = H + ((size_t)b * N_ + ng * 32) * E_ + e;
#pragma unroll 1
    for (int r = 0; r < REP; ++r) {
        asm volatile("" ::: "memory");
        uint32_t w = 0;
#pragma unroll
        for (int i = 0; i < 32; ++i) w |= (hp[(size_t)i * E_] > 0.5f) ? (1u << i) : 0u;
        HT[((size_t)b * (N_ / 32) + ng) * E_ + e] = w;
    }
}

// ---------------------------------------------------------------------------
// prep: rd_n (ballot over HT rows), rs_e (popcount over HT cols), WTb.
// ---------------------------------------------------------------------------
template <int REP>
__global__ void prep_kernel(const float* __restrict__ W, const uint32_t* __restrict__ HT,
                            uint16_t* __restrict__ WTb, float* __restrict__ rs_e,
                            float* __restrict__ rd_n) {
    const int blk = blockIdx.x, t = threadIdx.x;
#pragma unroll 1
    for (int r = 0; r < REP; ++r) {
        asm volatile("" ::: "memory");
        if (blk < 256) {
            const int wave = t >> 6, lane = t & 63;
            const int wid  = blk * 4 + wave;          // 0..1023 = (b, ng)
            const int b = wid >> 7, ng = wid & 127;
            const uint32_t* p = HT + ((size_t)b * (N_ / 32) + ng) * E_;
            int cnt = 0;
#pragma unroll 1
            for (int c8 = 0; c8 < E_ / 64; ++c8) {
                const uint32_t w = p[c8 * 64 + lane];
#pragma unroll
                for (int i = 0; i < 32; ++i) {
                    unsigned long long m = __ballot((w >> i) & 1u);
                    if (lane == i) cnt += __popcll(m);
                }
            }
            if (lane < 32)
                rd_n[(size_t)b * N_ + ng * 32 + lane] = (cnt > 0) ? 1.f / (float)cnt : 0.f;
        } else if (blk < 320) {
            const int i = (blk - 256) * 256 + t;      // 0..16383 = (b, e)
            const int b = i >> 11, e = i & 2047;
            const uint32_t* p = HT + (size_t)b * (N_ / 32) * E_ + e;
            int s = 0;
#pragma unroll 1
            for (int ng = 0; ng < N_ / 32; ++ng) s += __popc(p[(size_t)ng * E_]);
            rs_e[i] = (s > 0) ? 1.f / (float)s : 0.f;
        } else {
            const int i = (blk - 320) * 256 + t;      // 0..16383 = c*128+k
            const int c = i >> 7, k = i & 127;
            WTb[i] = bf16_rne(W[k * C_ + c]);
        }
    }
}

// ---------------------------------------------------------------------------
// N-SPLIT MFMA GEMM, all-register 4-deep pipeline (round-6 structure), plus
// ablation variants (VAR) for the round-7 diagnosis:
//  VAR 0: full kernel
//  VAR 1: noMFMA  -- loads + mkfrag; frags/bq kept live via asm "v" (rule #17)
//  VAR 2: noVALU  -- real loads + MFMA; mkfrag replaced by 4-mov splat of aw
//                    (loads stay live through the splat->MFMA dependence)
//  VAR 3: noMEM   -- loads only in prologue; asm "+v" touch on aw each step
//                    forces mkfrag re-materialization (anti-CSE)
//  MODE 0 (fc) : A = x fp32,    B = WTb,  out bf16 C^T xwbT (+bias)
//  MODE 1 (v2e): A = H^T bits,  B = xwbT, out bf16 C^T ebfT (x rs_e)
//  MODE 2 (e2v): A = H bits,    B = ebfT, out fp32 row-major (x rd_n)
// ---------------------------------------------------------------------------

#define LOADA(S, k0_) do {                                                            \
    if constexpr (MODE == 0) {                                                        \
        _Pragma("unroll")                                                             \
        for (int g = 0; g < NG; ++g) {                                                \
            const float* ap = Ax + ((size_t)batch * N_ + m0 + g * 16 + l15) * C_ + (k0_) + quad * 8; \
            const float4 f0 = *(const float4*)ap;                                     \
            const float4 f1 = *(const float4*)(ap + 4);                               \
            af##S[g*8+0]=f0.x; af##S[g*8+1]=f0.y; af##S[g*8+2]=f0.z; af##S[g*8+3]=f0.w; \
            af##S[g*8+4]=f1.x; af##S[g*8+5]=f1.y; af##S[g*8+6]=f1.z; af##S[g*8+7]=f1.w; \
        }                                                                             \
    } else if constexpr (MODE == 1) {                                                 \
        const uint32_t* p = Hp + (size_t)((k0_) >> 5) * E_ + m0 + l15;                \
        _Pragma("unroll")                                                             \
        for (int g = 0; g < NG; ++g) aw##S[g] = p[g * 16];                            \
    } else {                                                                          \
        const uint32_t* p = Hp + (size_t)(m0 >> 5) * E_ + (k0_) + quad * 8;           \
        _Pragma("unroll")                                                             \
        for (int r = 0; r < NG / 2; ++r) {                                            \
            axl##S[r] = *(const uint4*)(p + r * E_);                                  \
            axh##S[r] = *(const uint4*)(p + r * E_ + 4);                              \
        }                                                                             \
    } } while (0)

#define LOADB(S, k0_) do {                                                            \
    _Pragma("unroll")                                                                 \
    for (int j2 = 0; j2 < NJW; ++j2)                                                  \
        bq##S[j2] = *(const bf16x8*)&Bp[(size_t)((jw + j2) * 16 + l15) * K + (k0_) + quad * 8]; \
    } while (0)

#define MKFRAGS(S, A)                                                                 \
    bf16x8 A[NG];                                                                     \
    do {                                                                              \
    if constexpr (VAR == 2) {                                                         \
        _Pragma("unroll")                                                             \
        for (int g = 0; g < NG; ++g) {                                                \
            const uint32_t wv = aw##S[g];                                             \
            uint4 qq = make_uint4(wv, wv, wv, wv);                                    \
            A[g] = __builtin_bit_cast(bf16x8, qq);                                    \
        }                                                                             \
    } else if constexpr (MODE == 0) {                                                 \
        _Pragma("unroll")                                                             \
        for (int g = 0; g < NG; ++g)                                                  \
            { _Pragma("unroll")                                                       \
              for (int jj = 0; jj < 8; ++jj) A[g][jj] = (short)bf16_rne(af##S[g*8+jj]); } \
    } else if constexpr (MODE == 1) {                                                 \
        _Pragma("unroll")                                                             \
        for (int g = 0; g < NG; ++g) {                                                \
            const uint32_t w = aw##S[g];                                              \
            _Pragma("unroll")                                                         \
            for (int jj = 0; jj < 8; ++jj)                                            \
                A[g][jj] = (short)(((w >> (quad * 8 + jj)) & 1u) ? 0x3F80 : 0);       \
        }                                                                             \
    } else {                                                                          \
        _Pragma("unroll")                                                             \
        for (int g = 0; g < NG; ++g) {                                                \
            const int row = g >> 1, bit = (g & 1) * 16 + l15;                         \
            const uint32_t u[8] = {axl##S[row].x, axl##S[row].y, axl##S[row].z, axl##S[row].w, \
                                   axh##S[row].x, axh##S[row].y, axh##S[row].z, axh##S[row].w}; \
            _Pragma("unroll")                                                         \
            for (int jj = 0; jj < 8; ++jj)                                            \
                A[g][jj] = (short)(((u[jj] >> bit) & 1u) ? 0x3F80 : 0);               \
        }                                                                             \
    } } while (0)

#define TOUCHA(S) do { if constexpr (VAR == 3 && MODE == 1) {                         \
    _Pragma("unroll")                                                                 \
    for (int g = 0; g < NG; ++g) asm volatile("" : "+v"(aw##S[g])); } } while (0)

template <int MODE, int REP, int VAR>
__device__ __attribute__((always_inline))
void gemm_body(const float* __restrict__ Ax, const uint32_t* __restrict__ HT,
               const uint16_t* __restrict__ Btb, const float* __restrict__ bias,
               const float* __restrict__ rcp, uint16_t* __restrict__ outT,
               float* __restrict__ outF) {
    constexpr int K   = (MODE == 0) ? C_ : (MODE == 1) ? N_ : E_;
    constexpr int SW  = K / KT;                   // 4 / 128 / 64 steps, full K per wave
    constexpr int OLD = (MODE == 0) ? N_ : E_;
    constexpr int RL  = (MODE == 1) ? E_ : N_;
    constexpr int NG  = MT / 16;                  // 4 m-groups per wave
    static_assert(SW >= 4 && SW % 4 == 0, "pipeline needs SW multiple of 4");

    const int t = threadIdx.x, wave = t >> 6, lane = t & 63;
    const int l15 = lane & 15, quad = lane >> 4;
    const int batch = blockIdx.x & 7;             // batch -> XCD: panel stays in one L2
    const int m0 = (blockIdx.x >> 3) * MT;
    const int jw = wave * NJW;                    // first owned col-tile

    const uint16_t* Bp = Btb + (MODE == 0 ? (size_t)0 : (size_t)batch * C_ * K);
    const uint32_t* Hp = HT + (size_t)batch * (N_ / 32) * E_;

    f32x4 acc[NG * NJW];
    float    af0[NG * 8], af1[NG * 8], af2[NG * 8], af3[NG * 8];
    uint32_t aw0[NG], aw1[NG], aw2[NG], aw3[NG];
    uint4    axl0[NG / 2], axh0[NG / 2], axl1[NG / 2], axh1[NG / 2];
    uint4    axl2[NG / 2], axh2[NG / 2], axl3[NG / 2], axh3[NG / 2];
    bf16x8   bq0[NJW], bq1[NJW], bq2[NJW], bq3[NJW];

    auto mfma_all = [&](const bf16x8 (&A)[NG], const bf16x8 (&bv)[NJW])
        __attribute__((always_inline)) {
        if constexpr (VAR == 1) {
#pragma unroll
            for (int g = 0; g < NG; ++g)
                asm volatile("" :: "v"(__builtin_bit_cast(u32x4, A[g])));
#pragma unroll
            for (int j2 = 0; j2 < NJW; ++j2)
                asm volatile("" :: "v"(__builtin_bit_cast(u32x4, bv[j2])));
        } else {
#pragma unroll
            for (int j2 = 0; j2 < NJW; ++j2)
#pragma unroll
                for (int g = 0; g < NG; ++g)
                    acc[g * NJW + j2] = __builtin_amdgcn_mfma_f32_16x16x32_bf16(A[g], bv[j2], acc[g * NJW + j2], 0, 0, 0);
        }
    };

#pragma unroll 1
    for (int rep = 0; rep < REP; ++rep) {
        asm volatile("" ::: "memory");            // block cross-rep load CSE
#pragma unroll
        for (int i = 0; i < NG * NJW; ++i) acc[i] = (f32x4){0.f, 0.f, 0.f, 0.f};

        // prologue: 4 steps in flight
        LOADA(0, 0);      LOADB(0, 0);
        LOADA(1, KT);     LOADB(1, KT);
        LOADA(2, 2 * KT); LOADB(2, 2 * KT);
        LOADA(3, 3 * KT); LOADB(3, 3 * KT);

#pragma unroll 1
        for (int s = 0; s < SW - 4; s += 4) {
            { TOUCHA(0); MKFRAGS(0, A0); mfma_all(A0, bq0);
              if constexpr (VAR != 3) { LOADA(0, (s + 4) * KT); LOADB(0, (s + 4) * KT); } }
            { TOUCHA(1); MKFRAGS(1, A1); mfma_all(A1, bq1);
              if constexpr (VAR != 3) { LOADA(1, (s + 5) * KT); LOADB(1, (s + 5) * KT); } }
            { TOUCHA(2); MKFRAGS(2, A2); mfma_all(A2, bq2);
              if constexpr (VAR != 3) { LOADA(2, (s + 6) * KT); LOADB(2, (s + 6) * KT); } }
            { TOUCHA(3); MKFRAGS(3, A3); mfma_all(A3, bq3);
              if constexpr (VAR != 3) { LOADA(3, (s + 7) * KT); LOADB(3, (s + 7) * KT); } }
        }
        // drain: consume steps SW-4..SW-1
        { TOUCHA(0); MKFRAGS(0, A0); mfma_all(A0, bq0); }
        { TOUCHA(1); MKFRAGS(1, A1); mfma_all(A1, bq1); }
        { TOUCHA(2); MKFRAGS(2, A2); mfma_all(A2, bq2); }
        { TOUCHA(3); MKFRAGS(3, A3); mfma_all(A3, bq3); }

        // ---- per-wave epilogue (disjoint slices; no reduction, no barrier) ----
        float mul[NG][4];
        if constexpr (MODE != 0) {
#pragma unroll
            for (int g = 0; g < NG; ++g) {
                const float4 rv = *(const float4*)&rcp[(size_t)batch * RL + m0 + g * 16 + quad * 4];
                mul[g][0] = rv.x; mul[g][1] = rv.y; mul[g][2] = rv.z; mul[g][3] = rv.w;
            }
        }
#pragma unroll
        for (int g = 0; g < NG; ++g) {
            const int row = m0 + g * 16 + quad * 4;
            if constexpr (MODE == 2) {
                float* op = outF + ((size_t)batch * N_ + row) * C_;
#pragma unroll
                for (int j2 = 0; j2 < NJW; ++j2) {
                    const int c = (jw + j2) * 16 + l15;
#pragma unroll
                    for (int r = 0; r < 4; ++r) op[(size_t)r * C_ + c] = acc[g * NJW + j2][r] * mul[g][r];
                }
            } else {
#pragma unroll
                for (int j2 = 0; j2 < NJW; ++j2) {
                    const int c = (jw + j2) * 16 + l15;
                    float v0, v1, v2, v3;
                    if constexpr (MODE == 0) {
                        float bb = bias[c];
                        v0 = acc[g * NJW + j2][0] + bb; v1 = acc[g * NJW + j2][1] + bb;
                        v2 = acc[g * NJW + j2][2] + bb; v3 = acc[g * NJW + j2][3] + bb;
                    } else {
                        v0 = acc[g * NJW + j2][0] * mul[g][0]; v1 = acc[g * NJW + j2][1] * mul[g][1];
                        v2 = acc[g * NJW + j2][2] * mul[g][2]; v3 = acc[g * NJW + j2][3] * mul[g][3];
                    }
                    uint32_t q0 = (uint32_t)bf16_rne(v0) | ((uint32_t)bf16_rne(v1) << 16);
                    uint32_t q1 = (uint32_t)bf16_rne(v2) | ((uint32_t)bf16_rne(v3) << 16);
                    uint16_t* op = outT + ((size_t)batch * C_ + c) * OLD + row;
                    *(uint2*)op = make_uint2(q0, q1);
                }
            }
        }
    }
}

// Production kernels
__global__ __launch_bounds__(256, 2)
void fc_k(const float* __restrict__ Ax, const uint16_t* __restrict__ Btb,
          const float* __restrict__ bias, uint16_t* __restrict__ outT) {
    gemm_body<0, 12, 0>(Ax, nullptr, Btb, bias, nullptr, outT, nullptr);  // REP=12 diag
}
__global__ __launch_bounds__(256, 2)
void v2e_k(const uint32_t* __restrict__ HT, const uint16_t* __restrict__ Btb,
           const float* __restrict__ rcp, uint16_t* __restrict__ outT) {
    gemm_body<1, 1, 0>(nullptr, HT, Btb, nullptr, rcp, outT, nullptr);
}
__global__ __launch_bounds__(256, 2)
void e2v_k(const uint32_t* __restrict__ HT, const uint16_t* __restrict__ Btb,
           const float* __restrict__ rcp, float* __restrict__ outF) {
    gemm_body<2, 1, 0>(nullptr, HT, Btb, nullptr, rcp, nullptr, outF);
}
// Diagnostic kernels (write to ws scratch; distinct names -> attributable rows)
__global__ __launch_bounds__(256, 2)
void v2e_full(const uint32_t* __restrict__ HT, const uint16_t* __restrict__ Btb,
              const float* __restrict__ rcp, uint16_t* __restrict__ outT) {
    gemm_body<1, 4, 0>(nullptr, HT, Btb, nullptr, rcp, outT, nullptr);
}
__global__ __launch_bounds__(256, 2)
void v2e_nomfma(const uint32_t* __restrict__ HT, const uint16_t* __restrict__ Btb,
                const float* __restrict__ rcp, uint16_t* __restrict__ outT) {
    gemm_body<1, 6, 1>(nullptr, HT, Btb, nullptr, rcp, outT, nullptr);
}
__global__ __launch_bounds__(256, 2)
void v2e_novalu(const uint32_t* __restrict__ HT, const uint16_t* __restrict__ Btb,
                const float* __restrict__ rcp, uint16_t* __restrict__ outT) {
    gemm_body<1, 6, 2>(nullptr, HT, Btb, nullptr, rcp, outT, nullptr);
}
__global__ __launch_bounds__(256, 2)
void v2e_nomem(const uint32_t* __restrict__ HT, const uint16_t* __restrict__ Btb,
               const float* __restrict__ rcp, uint16_t* __restrict__ outT) {
    gemm_body<1, 12, 3>(nullptr, HT, Btb, nullptr, rcp, outT, nullptr);
}

// ---------------------------------------------------------------------------
extern "C" void kernel_launch(void* const* d_in, const int* in_sizes, int n_in,
                              void* d_out, int out_size, void* d_ws, size_t ws_size,
                              hipStream_t stream) {
    const float* x    = (const float*)d_in[0];   // [8,4096,128]
    const float* H    = (const float*)d_in[1];   // [8,4096,2048]
    const float* W    = (const float*)d_in[2];   // [128,128]
    const float* bias = (const float*)d_in[3];   // [128]
    float* out = (float*)d_out;                  // [8,4096,128]

    // ws (~12.3 MB used): HT 8MB | WTb 32KB | ebfT 4MB | rs_e 64KB | rd_n 128KB
    uint32_t* HT   = (uint32_t*)d_ws;
    uint16_t* WTb  = (uint16_t*)(HT + HT_E);
    uint16_t* ebfT = WTb + WT_E;
    float*    rs_e = (float*)(ebfT + EBF_E);
    float*    rd_n = rs_e + RS_E;
    uint16_t* xwbT = (uint16_t*)d_out;           // d_out is dead scratch until e2v

    pack_kernel<4><<<dim3(8192), dim3(256), 0, stream>>>(H, HT);
    prep_kernel<12><<<dim3(384), dim3(256), 0, stream>>>(W, HT, WTb, rs_e, rd_n);
    fc_k <<<dim3(8 * (N_ / MT)), dim3(256), 0, stream>>>(x, WTb, bias, xwbT);
    v2e_k<<<dim3(8 * (E_ / MT)), dim3(256), 0, stream>>>(HT, xwbT, rs_e, ebfT);
    if (ws_size >= (64ull << 20)) {              // diagnostics into scratch @32MB
        uint16_t* scr = (uint16_t*)((uint8_t*)d_ws + (32ull << 20));
        v2e_full  <<<dim3(8 * (E_ / MT)), dim3(256), 0, stream>>>(HT, xwbT, rs_e, scr);
        v2e_nomfma<<<dim3(8 * (E_ / MT)), dim3(256), 0, stream>>>(HT, xwbT, rs_e, scr);
        v2e_novalu<<<dim3(8 * (E_ / MT)), dim3(256), 0, stream>>>(HT, xwbT, rs_e, scr);
        v2e_nomem <<<dim3(8 * (E_ / MT)), dim3(256), 0, stream>>>(HT, xwbT, rs_e, scr);
    }
    e2v_k<<<dim3(8 * (N_ / MT)), dim3(256), 0, stream>>>(HT, ebfT, rd_n, out);
}

// Round 8
// 472.297 us; speedup vs baseline: 3.9352x; 3.9352x over previous
//
#include <hip/hip_runtime.h>
#include <stdint.h>

// Problem constants
constexpr int B_ = 8, N_ = 4096, E_ = 2048, C_ = 128;
constexpr int KT = 32;     // K per MFMA step
constexpr int MT = 64;     // M rows per block (4 x 16-row groups)
constexpr int NJW = 2;     // col-tiles per wave (8 tiles / 4 waves) -- N-split

typedef short bf16x8 __attribute__((ext_vector_type(8)));
typedef float f32x4  __attribute__((ext_vector_type(4)));
typedef unsigned int u32x4 __attribute__((ext_vector_type(4)));

__device__ inline uint16_t bf16_rne(float f) {
    uint32_t u = __builtin_bit_cast(uint32_t, f);
    return (uint16_t)((u + 0x7FFFu + ((u >> 16) & 1u)) >> 16);
}

constexpr size_t BIT_B = (size_t)(N_ / 32) * E_;       // 262144 dwords per batch (== (E_/32)*N_)
constexpr size_t HT_E  = (size_t)B_ * BIT_B;           // 2M dwords = 8 MB
constexpr size_t WT_E  = (size_t)C_ * C_;              // 16384 bf16
constexpr size_t EBF_E = (size_t)B_ * C_ * E_;         // 2M bf16 = 4 MB
constexpr size_t RS_E  = (size_t)B_ * E_;              // 16K floats
constexpr size_t RD_E  = (size_t)B_ * N_;              // 32K floats

// ---------------------------------------------------------------------------
// pack: H (fp32 0/1) -> HT[b][n/32][e] (bit = n%32)  AND, via in-register
// 32x ballot transpose, HTe[b][e/32][n] (bit = e%32). HBM-bound (268 MB read).
// ---------------------------------------------------------------------------
__global__ void pack_kernel(const float* __restrict__ H, uint32_t* __restrict__ HT,
                            uint32_t* __restrict__ HTe) {
    const int t  = threadIdx.x;
    const int eg = blockIdx.x & 7;
    const int ng = (blockIdx.x >> 3) & 127;
    const int b  = blockIdx.x >> 10;
    const int e  = eg * 256 + t;
    const float* hp = H + ((size_t)b * N_ + ng * 32) * E_ + e;
    uint32_t w = 0;
#pragma unroll
    for (int i = 0; i < 32; ++i) w |= (hp[(size_t)i * E_] > 0.5f) ? (1u << i) : 0u;
    HT[((size_t)b * (N_ / 32) + ng) * E_ + e] = w;

    // e-packed transpose: wave (64 e's) x 32 n-bits -> 64 HTe words
    const int lane  = t & 63;
    const int ebase = eg * 256 + (t >> 6) * 64;
    uint32_t val = 0;
#pragma unroll
    for (int i = 0; i < 32; ++i) {
        unsigned long long m = __ballot((w >> i) & 1u);
        uint32_t half = (lane < 32) ? (uint32_t)m : (uint32_t)(m >> 32);
        if ((lane & 31) == i) val = half;
    }
    HTe[((size_t)b * (E_ / 32) + (ebase >> 5) + (lane >> 5)) * N_ + ng * 32 + (lane & 31)] = val;
}

// ---------------------------------------------------------------------------
// prep: rd_n = 0.5/deg(n) (popc over HTe rows), rs_e = 0.5/deg(e) (popc over
// HT rows), WTb = bf16(W^T). The 0.5 compensates the bit-value 2.0 in the
// GEMMs (exact power-of-2 fold -> bit-identical numerics).
// ---------------------------------------------------------------------------
__global__ void prep_kernel(const float* __restrict__ W, const uint32_t* __restrict__ HT,
                            const uint32_t* __restrict__ HTe, uint16_t* __restrict__ WTb,
                            float* __restrict__ rs_e, float* __restrict__ rd_n) {
    const int blk = blockIdx.x, t = threadIdx.x;
    if (blk < 128) {                              // rd_n: 32768 = (b, n)
        const int i = blk * 256 + t;
        const int b = i >> 12, n = i & 4095;
        const uint32_t* p = HTe + (size_t)b * BIT_B + n;
        int s = 0;
#pragma unroll 1
        for (int ew = 0; ew < E_ / 32; ++ew) s += __popc(p[(size_t)ew * N_]);
        rd_n[i] = (s > 0) ? 0.5f / (float)s : 0.f;
    } else if (blk < 192) {                       // rs_e: 16384 = (b, e)
        const int i = (blk - 128) * 256 + t;
        const int b = i >> 11, e = i & 2047;
        const uint32_t* p = HT + (size_t)b * BIT_B + e;
        int s = 0;
#pragma unroll 1
        for (int ng = 0; ng < N_ / 32; ++ng) s += __popc(p[(size_t)ng * E_]);
        rs_e[i] = (s > 0) ? 0.5f / (float)s : 0.f;
    } else if (blk < 256) {                       // WTb: 16384 = c*128+k
        const int i = (blk - 192) * 256 + t;
        const int c = i >> 7, k = i & 127;
        WTb[i] = bf16_rne(W[k * C_ + c]);
    }
}

// ---------------------------------------------------------------------------
// N-SPLIT MFMA GEMM, all-register 4-deep pipeline. Round-8 change: the bit->
// bf16 expansion (proven VALU bottleneck: R7 ablation v2e_nomem = 34 us/rep
// @ VALUBusy 78%, ~8 VALU/elem) is replaced by a nibble-spread + v_perm path
// (~1.5 VALU/elem) emitting bf16 2.0 per set bit; the x2 is folded into the
// pre-halved rcp arrays. e2v now reads HTe (e-packed bits) so both H-GEMMs
// share this fast path.
//  MODE 0 (fc) : A = x fp32,        B = WTb,  out bf16 C^T xwbT (+bias)
//  MODE 1 (v2e): A = HT bits (2.0), B = xwbT, out bf16 C^T ebfT (x 0.5/s_e)
//  MODE 2 (e2v): A = HTe bits(2.0), B = ebfT, out fp32 row-major (x 0.5/d_n)
// ---------------------------------------------------------------------------

#define LOADA(S, k0_) do {                                                            \
    if constexpr (MODE == 0) {                                                        \
        _Pragma("unroll")                                                             \
        for (int g = 0; g < NG; ++g) {                                                \
            const float* ap = Ax + ((size_t)batch * N_ + m0 + g * 16 + l15) * C_ + (k0_) + quad * 8; \
            const float4 f0 = *(const float4*)ap;                                     \
            const float4 f1 = *(const float4*)(ap + 4);                               \
            af##S[g*8+0]=f0.x; af##S[g*8+1]=f0.y; af##S[g*8+2]=f0.z; af##S[g*8+3]=f0.w; \
            af##S[g*8+4]=f1.x; af##S[g*8+5]=f1.y; af##S[g*8+6]=f1.z; af##S[g*8+7]=f1.w; \
        }                                                                             \
    } else {                                                                          \
        const uint32_t* p = Hp + (size_t)((k0_) >> 5) * RL + m0 + l15;                \
        _Pragma("unroll")                                                             \
        for (int g = 0; g < NG; ++g) aw##S[g] = p[g * 16];                            \
    } } while (0)

#define LOADB(S, k0_) do {                                                            \
    _Pragma("unroll")                                                                 \
    for (int j2 = 0; j2 < NJW; ++j2)                                                  \
        bq##S[j2] = *(const bf16x8*)&Bp[(size_t)((jw + j2) * 16 + l15) * K + (k0_) + quad * 8]; \
    } while (0)

// bit->bf16(2.0) fast expansion: nibble * 0x204081 spreads bit i to byte i;
// &0x01010101 <<6 makes bytes 0x40*bit; v_perm interleaves with zero bytes ->
// packed bf16 pairs {0x4000*b_even, 0x4000*b_odd}. 12 VALU per 8 elements.
#define MKFRAGS(S, A)                                                                 \
    bf16x8 A[NG];                                                                     \
    do {                                                                              \
    if constexpr (MODE == 0) {                                                        \
        _Pragma("unroll")                                                             \
        for (int g = 0; g < NG; ++g)                                                  \
            { _Pragma("unroll")                                                       \
              for (int jj = 0; jj < 8; ++jj) A[g][jj] = (short)bf16_rne(af##S[g*8+jj]); } \
    } else {                                                                          \
        const int qs = quad * 8;                                                      \
        _Pragma("unroll")                                                             \
        for (int g = 0; g < NG; ++g) {                                                \
            const uint32_t wv = aw##S[g];                                             \
            const uint32_t nb0 = (wv >> qs) & 0xFu;                                   \
            const uint32_t nb1 = (wv >> (qs + 4)) & 0xFu;                             \
            const uint32_t s0m = ((nb0 * 0x204081u) & 0x01010101u) << 6;              \
            const uint32_t s1m = ((nb1 * 0x204081u) & 0x01010101u) << 6;              \
            u32x4 qq = { __builtin_amdgcn_perm(s0m, 0u, 0x05000400u),                 \
                         __builtin_amdgcn_perm(s0m, 0u, 0x07000600u),                 \
                         __builtin_amdgcn_perm(s1m, 0u, 0x05000400u),                 \
                         __builtin_amdgcn_perm(s1m, 0u, 0x07000600u) };               \
            A[g] = __builtin_bit_cast(bf16x8, qq);                                    \
        }                                                                             \
    } } while (0)

template <int MODE>
__device__ __attribute__((always_inline))
void gemm_body(const float* __restrict__ Ax, const uint32_t* __restrict__ bits,
               const uint16_t* __restrict__ Btb, const float* __restrict__ bias,
               const float* __restrict__ rcp, uint16_t* __restrict__ outT,
               float* __restrict__ outF) {
    constexpr int K   = (MODE == 0) ? C_ : (MODE == 1) ? N_ : E_;
    constexpr int SW  = K / KT;                   // 4 / 128 / 64 steps, full K per wave
    constexpr int OLD = (MODE == 0) ? N_ : E_;
    constexpr int RL  = (MODE == 1) ? E_ : N_;    // bit-array row stride == rcp stride
    constexpr int NG  = MT / 16;                  // 4 m-groups per wave
    static_assert(SW >= 4 && SW % 4 == 0, "pipeline needs SW multiple of 4");

    const int t = threadIdx.x, wave = t >> 6, lane = t & 63;
    const int l15 = lane & 15, quad = lane >> 4;
    const int batch = blockIdx.x & 7;             // batch -> XCD: panel stays in one L2
    const int m0 = (blockIdx.x >> 3) * MT;
    const int jw = wave * NJW;                    // first owned col-tile

    const uint16_t* Bp = Btb + (MODE == 0 ? (size_t)0 : (size_t)batch * C_ * K);
    const uint32_t* Hp = bits + (size_t)batch * BIT_B;

    f32x4 acc[NG * NJW];
    float    af0[NG * 8], af1[NG * 8], af2[NG * 8], af3[NG * 8];
    uint32_t aw0[NG], aw1[NG], aw2[NG], aw3[NG];
    bf16x8   bq0[NJW], bq1[NJW], bq2[NJW], bq3[NJW];

    auto mfma_all = [&](const bf16x8 (&A)[NG], const bf16x8 (&bv)[NJW])
        __attribute__((always_inline)) {
#pragma unroll
        for (int j2 = 0; j2 < NJW; ++j2)
#pragma unroll
            for (int g = 0; g < NG; ++g)
                acc[g * NJW + j2] = __builtin_amdgcn_mfma_f32_16x16x32_bf16(A[g], bv[j2], acc[g * NJW + j2], 0, 0, 0);
    };

#pragma unroll
    for (int i = 0; i < NG * NJW; ++i) acc[i] = (f32x4){0.f, 0.f, 0.f, 0.f};

    // prologue: 4 steps in flight (3-step prefetch lead in steady state)
    LOADA(0, 0);      LOADB(0, 0);
    LOADA(1, KT);     LOADB(1, KT);
    LOADA(2, 2 * KT); LOADB(2, 2 * KT);
    LOADA(3, 3 * KT); LOADB(3, 3 * KT);

#pragma unroll 1
    for (int s = 0; s < SW - 4; s += 4) {
        { MKFRAGS(0, A0); mfma_all(A0, bq0); LOADA(0, (s + 4) * KT); LOADB(0, (s + 4) * KT); }
        { MKFRAGS(1, A1); mfma_all(A1, bq1); LOADA(1, (s + 5) * KT); LOADB(1, (s + 5) * KT); }
        { MKFRAGS(2, A2); mfma_all(A2, bq2); LOADA(2, (s + 6) * KT); LOADB(2, (s + 6) * KT); }
        { MKFRAGS(3, A3); mfma_all(A3, bq3); LOADA(3, (s + 7) * KT); LOADB(3, (s + 7) * KT); }
    }
    // drain: consume steps SW-4..SW-1
    { MKFRAGS(0, A0); mfma_all(A0, bq0); }
    { MKFRAGS(1, A1); mfma_all(A1, bq1); }
    { MKFRAGS(2, A2); mfma_all(A2, bq2); }
    { MKFRAGS(3, A3); mfma_all(A3, bq3); }

    // ---- per-wave epilogue (disjoint slices; no reduction, no barrier) ----
    float mul[NG][4];
    if constexpr (MODE != 0) {
#pragma unroll
        for (int g = 0; g < NG; ++g) {
            const float4 rv = *(const float4*)&rcp[(size_t)batch * RL + m0 + g * 16 + quad * 4];
            mul[g][0] = rv.x; mul[g][1] = rv.y; mul[g][2] = rv.z; mul[g][3] = rv.w;
        }
    }
#pragma unroll
    for (int g = 0; g < NG; ++g) {
        const int row = m0 + g * 16 + quad * 4;
        if constexpr (MODE == 2) {
            float* op = outF + ((size_t)batch * N_ + row) * C_;
#pragma unroll
            for (int j2 = 0; j2 < NJW; ++j2) {
                const int c = (jw + j2) * 16 + l15;
#pragma unroll
                for (int r = 0; r < 4; ++r) op[(size_t)r * C_ + c] = acc[g * NJW + j2][r] * mul[g][r];
            }
        } else {
#pragma unroll
            for (int j2 = 0; j2 < NJW; ++j2) {
                const int c = (jw + j2) * 16 + l15;
                float v0, v1, v2, v3;
                if constexpr (MODE == 0) {
                    float bb = bias[c];
                    v0 = acc[g * NJW + j2][0] + bb; v1 = acc[g * NJW + j2][1] + bb;
                    v2 = acc[g * NJW + j2][2] + bb; v3 = acc[g * NJW + j2][3] + bb;
                } else {
                    v0 = acc[g * NJW + j2][0] * mul[g][0]; v1 = acc[g * NJW + j2][1] * mul[g][1];
                    v2 = acc[g * NJW + j2][2] * mul[g][2]; v3 = acc[g * NJW + j2][3] * mul[g][3];
                }
                uint32_t q0 = (uint32_t)bf16_rne(v0) | ((uint32_t)bf16_rne(v1) << 16);
                uint32_t q1 = (uint32_t)bf16_rne(v2) | ((uint32_t)bf16_rne(v3) << 16);
                uint16_t* op = outT + ((size_t)batch * C_ + c) * OLD + row;
                *(uint2*)op = make_uint2(q0, q1);
            }
        }
    }
}

// Named wrappers -> attributable rocprof rows
__global__ __launch_bounds__(256, 2)
void fc_k(const float* __restrict__ Ax, const uint16_t* __restrict__ Btb,
          const float* __restrict__ bias, uint16_t* __restrict__ outT) {
    gemm_body<0>(Ax, nullptr, Btb, bias, nullptr, outT, nullptr);
}
__global__ __launch_bounds__(256, 2)
void v2e_k(const uint32_t* __restrict__ HT, const uint16_t* __restrict__ Btb,
           const float* __restrict__ rcp, uint16_t* __restrict__ outT) {
    gemm_body<1>(nullptr, HT, Btb, nullptr, rcp, outT, nullptr);
}
__global__ __launch_bounds__(256, 2)
void e2v_k(const uint32_t* __restrict__ HTe, const uint16_t* __restrict__ Btb,
           const float* __restrict__ rcp, float* __restrict__ outF) {
    gemm_body<2>(nullptr, HTe, Btb, nullptr, rcp, nullptr, outF);
}

// ---------------------------------------------------------------------------
extern "C" void kernel_launch(void* const* d_in, const int* in_sizes, int n_in,
                              void* d_out, int out_size, void* d_ws, size_t ws_size,
                              hipStream_t stream) {
    const float* x    = (const float*)d_in[0];   // [8,4096,128]
    const float* H    = (const float*)d_in[1];   // [8,4096,2048]
    const float* W    = (const float*)d_in[2];   // [128,128]
    const float* bias = (const float*)d_in[3];   // [128]
    float* out = (float*)d_out;                  // [8,4096,128]

    // ws (~20.3 MB): HT 8MB | HTe 8MB | WTb 32KB | ebfT 4MB | rs_e 64KB | rd_n 128KB
    uint32_t* HT   = (uint32_t*)d_ws;
    uint32_t* HTe  = HT + HT_E;
    uint16_t* WTb  = (uint16_t*)(HTe + HT_E);
    uint16_t* ebfT = WTb + WT_E;
    float*    rs_e = (float*)(ebfT + EBF_E);
    float*    rd_n = rs_e + RS_E;
    uint16_t* xwbT = (uint16_t*)d_out;           // d_out is dead scratch until e2v

    pack_kernel<<<dim3(8192), dim3(256), 0, stream>>>(H, HT, HTe);
    prep_kernel<<<dim3(256), dim3(256), 0, stream>>>(W, HT, HTe, WTb, rs_e, rd_n);
    fc_k <<<dim3(8 * (N_ / MT)), dim3(256), 0, stream>>>(x, WTb, bias, xwbT);
    v2e_k<<<dim3(8 * (E_ / MT)), dim3(256), 0, stream>>>(HT, xwbT, rs_e, ebfT);
    e2v_k<<<dim3(8 * (N_ / MT)), dim3(256), 0, stream>>>(HTe, ebfT, rd_n, out);
}

// Round 10
// 465.302 us; speedup vs baseline: 3.9944x; 1.0150x over previous
//
#include <hip/hip_runtime.h>
#include <stdint.h>

// Problem constants
constexpr int B_ = 8, N_ = 4096, E_ = 2048, C_ = 128;
constexpr int KT  = 32;    // K per MFMA step
constexpr int MT  = 64;    // M rows per block (4 x 16-row groups, all owned by every wave)
constexpr int NJW = 4;     // col-tiles per wave (2x2 split: k-half x col-half)
constexpr int LRP = 65;    // reduction LDS row stride (floats, +1 pad)

typedef short bf16x8 __attribute__((ext_vector_type(8)));
typedef float f32x4  __attribute__((ext_vector_type(4)));
typedef unsigned int u32x4 __attribute__((ext_vector_type(4)));

__device__ inline uint16_t bf16_rne(float f) {
    uint32_t u = __builtin_bit_cast(uint32_t, f);
    return (uint16_t)((u + 0x7FFFu + ((u >> 16) & 1u)) >> 16);
}

constexpr size_t BIT_B = (size_t)(N_ / 32) * E_;       // 262144 dwords per batch
constexpr size_t HT_E  = (size_t)B_ * BIT_B;           // 2M dwords = 8 MB
constexpr size_t WT_E  = (size_t)C_ * C_;              // 16384 bf16
constexpr size_t EBF_E = (size_t)B_ * C_ * E_;         // 2M bf16 = 4 MB
constexpr size_t RS_E  = (size_t)B_ * E_;              // 16K floats
constexpr size_t RD_E  = (size_t)B_ * N_;              // 32K floats

// ---------------------------------------------------------------------------
// pack: H (fp32 0/1) -> HT[b][n/32][e] (bit = n%32) AND, via in-register
// 32x ballot transpose, HTe[b][e/32][n] (bit = e%32). HBM-bound (268 MB read).
// ---------------------------------------------------------------------------
__global__ void pack_kernel(const float* __restrict__ H, uint32_t* __restrict__ HT,
                            uint32_t* __restrict__ HTe) {
    const int t  = threadIdx.x;
    const int eg = blockIdx.x & 7;
    const int ng = (blockIdx.x >> 3) & 127;
    const int b  = blockIdx.x >> 10;
    const int e  = eg * 256 + t;
    const float* hp = H + ((size_t)b * N_ + ng * 32) * E_ + e;
    uint32_t w = 0;
#pragma unroll
    for (int i = 0; i < 32; ++i) w |= (hp[(size_t)i * E_] > 0.5f) ? (1u << i) : 0u;
    HT[((size_t)b * (N_ / 32) + ng) * E_ + e] = w;

    // e-packed transpose: wave (64 e's) x 32 n-bits -> 64 HTe words
    const int lane  = t & 63;
    const int ebase = eg * 256 + (t >> 6) * 64;
    uint32_t val = 0;
#pragma unroll
    for (int i = 0; i < 32; ++i) {
        unsigned long long m = __ballot((w >> i) & 1u);
        uint32_t half = (lane < 32) ? (uint32_t)m : (uint32_t)(m >> 32);
        if ((lane & 31) == i) val = half;
    }
    HTe[((size_t)b * (E_ / 32) + (ebase >> 5) + (lane >> 5)) * N_ + ng * 32 + (lane & 31)] = val;
}

// ---------------------------------------------------------------------------
// prep: rd_n = 0.5/deg(n) (popc over HTe cols), rs_e = 0.5/deg(e) (popc over
// HT cols), WTb = bf16(W^T). The 0.5 compensates bit-value 2.0 in the GEMMs.
// ---------------------------------------------------------------------------
__global__ void prep_kernel(const float* __restrict__ W, const uint32_t* __restrict__ HT,
                            const uint32_t* __restrict__ HTe, uint16_t* __restrict__ WTb,
                            float* __restrict__ rs_e, float* __restrict__ rd_n) {
    const int blk = blockIdx.x, t = threadIdx.x;
    if (blk < 128) {                              // rd_n: 32768 = (b, n)
        const int i = blk * 256 + t;
        const int b = i >> 12, n = i & 4095;
        const uint32_t* p = HTe + (size_t)b * BIT_B + n;
        int s = 0;
#pragma unroll 1
        for (int ew = 0; ew < E_ / 32; ++ew) s += __popc(p[(size_t)ew * N_]);
        rd_n[i] = (s > 0) ? 0.5f / (float)s : 0.f;
    } else if (blk < 192) {                       // rs_e: 16384 = (b, e)
        const int i = (blk - 128) * 256 + t;
        const int b = i >> 11, e = i & 2047;
        const uint32_t* p = HT + (size_t)b * BIT_B + e;
        int s = 0;
#pragma unroll 1
        for (int ng = 0; ng < N_ / 32; ++ng) s += __popc(p[(size_t)ng * E_]);
        rs_e[i] = (s > 0) ? 0.5f / (float)s : 0.f;
    } else if (blk < 256) {                       // WTb: 16384 = c*128+k
        const int i = (blk - 192) * 256 + t;
        const int c = i >> 7, k = i & 127;
        WTb[i] = bf16_rne(W[k * C_ + c]);
    }
}

// ---------------------------------------------------------------------------
// 2x2-SPLIT MFMA GEMM: wave = (k-half, col-half). Each wave owns 4 col-tiles
// and K/2 -> expanded A-fragments amortize over 16 MFMAs/step (the N-split's
// 4x A-expansion inflation undone) while B stays in a 4-deep named-register
// pipeline (R6 correctness model: compiler-scoreboarded waits, no LDS, no
// manual vmcnt). Cross-wave k-half reduction = ONE barrier via 33 KB LDS
// (waves 1,3 store; waves 0,2 add + write disjoint col-halves).
//  MODE 0 (fc) : A = x fp32,        B = WTb,  out bf16 C^T xwbT (+bias)
//  MODE 1 (v2e): A = HT bits (2.0), B = xwbT, out bf16 C^T ebfT (x 0.5/s_e)
//  MODE 2 (e2v): A = HTe bits(2.0), B = ebfT, out fp32 row-major (x 0.5/d_n)
// ---------------------------------------------------------------------------

#define LOADA(S, k0_) do {                                                            \
    if constexpr (MODE == 0) {                                                        \
        _Pragma("unroll")                                                             \
        for (int g = 0; g < NG; ++g) {                                                \
            const float* ap = Ax + ((size_t)batch * N_ + m0 + g * 16 + l15) * C_ + (k0_) + quad * 8; \
            const float4 f0 = *(const float4*)ap;                                     \
            const float4 f1 = *(const float4*)(ap + 4);                               \
            af##S[g*8+0]=f0.x; af##S[g*8+1]=f0.y; af##S[g*8+2]=f0.z; af##S[g*8+3]=f0.w; \
            af##S[g*8+4]=f1.x; af##S[g*8+5]=f1.y; af##S[g*8+6]=f1.z; af##S[g*8+7]=f1.w; \
        }                                                                             \
    } else {                                                                          \
        const uint32_t* p = Hp + (size_t)((k0_) >> 5) * RL + m0 + l15;                \
        _Pragma("unroll")                                                             \
        for (int g = 0; g < NG; ++g) aw##S[g] = p[g * 16];                            \
    } } while (0)

#define LOADB(S, k0_) do {                                                            \
    _Pragma("unroll")                                                                 \
    for (int j2 = 0; j2 < NJW; ++j2)                                                  \
        bq##S[j2] = *(const bf16x8*)&Bp[(size_t)((jw + j2) * 16 + l15) * K + (k0_) + quad * 8]; \
    } while (0)

// bit->bf16(2.0) fast expansion: nibble * 0x204081 spreads bit i to byte i;
// &0x01010101 <<6 makes bytes 0x40*bit; v_perm zero-interleaves -> packed
// bf16 pairs. 12 VALU per 8 elements (vs ~64 for the naive path, R7 ablation).
#define MKFRAGS(S, A)                                                                 \
    bf16x8 A[NG];                                                                     \
    do {                                                                              \
    if constexpr (MODE == 0) {                                                        \
        _Pragma("unroll")                                                             \
        for (int g = 0; g < NG; ++g)                                                  \
            { _Pragma("unroll")                                                       \
              for (int jj = 0; jj < 8; ++jj) A[g][jj] = (short)bf16_rne(af##S[g*8+jj]); } \
    } else {                                                                          \
        const int qs = quad * 8;                                                      \
        _Pragma("unroll")                                                             \
        for (int g = 0; g < NG; ++g) {                                                \
            const uint32_t wv = aw##S[g];                                             \
            const uint32_t nb0 = (wv >> qs) & 0xFu;                                   \
            const uint32_t nb1 = (wv >> (qs + 4)) & 0xFu;                             \
            const uint32_t s0m = ((nb0 * 0x204081u) & 0x01010101u) << 6;              \
            const uint32_t s1m = ((nb1 * 0x204081u) & 0x01010101u) << 6;              \
            u32x4 qq = { __builtin_amdgcn_perm(s0m, 0u, 0x05000400u),                 \
                         __builtin_amdgcn_perm(s0m, 0u, 0x07000600u),                 \
                         __builtin_amdgcn_perm(s1m, 0u, 0x05000400u),                 \
                         __builtin_amdgcn_perm(s1m, 0u, 0x07000600u) };               \
            A[g] = __builtin_bit_cast(bf16x8, qq);                                    \
        }                                                                             \
    } } while (0)

template <int MODE>
__device__ __attribute__((always_inline))
void gemm_body(const float* __restrict__ Ax, const uint32_t* __restrict__ bits,
               const uint16_t* __restrict__ Btb, const float* __restrict__ bias,
               const float* __restrict__ rcp, uint16_t* __restrict__ outT,
               float* __restrict__ outF) {
    constexpr int K   = (MODE == 0) ? C_ : (MODE == 1) ? N_ : E_;
    constexpr int KH  = K / 2;                    // per-wave K half
    constexpr int SW  = KH / KT;                  // 2 / 64 / 32 steps
    constexpr int OLD = (MODE == 0) ? N_ : E_;
    constexpr int RL  = (MODE == 1) ? E_ : N_;    // bit-row stride == rcp stride
    constexpr int NG  = MT / 16;                  // 4 m-groups per wave
    static_assert(SW == 2 || (SW >= 4 && SW % 4 == 0), "pipeline shape");

    __shared__ float R[2 * 64 * LRP];             // two 64x64(+pad) k-half partials

    const int t = threadIdx.x, wave = t >> 6, lane = t & 63;
    const int l15 = lane & 15, quad = lane >> 4;
    const int kh = wave & 1, jg = wave >> 1;      // k-half, col-half
    const int jw = jg * NJW;                      // first owned col-tile
    const int kwv = kh * KH;
    const int batch = blockIdx.x & 7;             // batch -> XCD: panel stays in one L2
    const int m0 = (blockIdx.x >> 3) * MT;

    const uint16_t* Bp = Btb + (MODE == 0 ? (size_t)0 : (size_t)batch * C_ * K);
    const uint32_t* Hp = bits + (size_t)batch * BIT_B;

    f32x4 acc[NG * NJW];
    // all four pipeline stages declared for every MODE (names must exist even
    // in constexpr-discarded branches; unused arrays cost nothing)
    float    af0[NG * 8], af1[NG * 8], af2[NG * 8], af3[NG * 8];
    uint32_t aw0[NG], aw1[NG], aw2[NG], aw3[NG];
    bf16x8   bq0[NJW], bq1[NJW], bq2[NJW], bq3[NJW];

    auto mfma_all = [&](const bf16x8 (&A)[NG], const bf16x8 (&bv)[NJW])
        __attribute__((always_inline)) {
#pragma unroll
        for (int j2 = 0; j2 < NJW; ++j2)
#pragma unroll
            for (int g = 0; g < NG; ++g)
                acc[g * NJW + j2] = __builtin_amdgcn_mfma_f32_16x16x32_bf16(A[g], bv[j2], acc[g * NJW + j2], 0, 0, 0);
    };

#pragma unroll
    for (int i = 0; i < NG * NJW; ++i) acc[i] = (f32x4){0.f, 0.f, 0.f, 0.f};

    if constexpr (SW >= 4) {
        // 4-deep register pipeline (3-step prefetch lead)
        LOADA(0, kwv);          LOADB(0, kwv);
        LOADA(1, kwv + KT);     LOADB(1, kwv + KT);
        LOADA(2, kwv + 2 * KT); LOADB(2, kwv + 2 * KT);
        LOADA(3, kwv + 3 * KT); LOADB(3, kwv + 3 * KT);
#pragma unroll 1
        for (int s = 0; s < SW - 4; s += 4) {
            { MKFRAGS(0, A0); mfma_all(A0, bq0); LOADA(0, kwv + (s + 4) * KT); LOADB(0, kwv + (s + 4) * KT); }
            { MKFRAGS(1, A1); mfma_all(A1, bq1); LOADA(1, kwv + (s + 5) * KT); LOADB(1, kwv + (s + 5) * KT); }
            { MKFRAGS(2, A2); mfma_all(A2, bq2); LOADA(2, kwv + (s + 6) * KT); LOADB(2, kwv + (s + 6) * KT); }
            { MKFRAGS(3, A3); mfma_all(A3, bq3); LOADA(3, kwv + (s + 7) * KT); LOADB(3, kwv + (s + 7) * KT); }
        }
        { MKFRAGS(0, A0); mfma_all(A0, bq0); }
        { MKFRAGS(1, A1); mfma_all(A1, bq1); }
        { MKFRAGS(2, A2); mfma_all(A2, bq2); }
        { MKFRAGS(3, A3); mfma_all(A3, bq3); }
    } else {
        // fc: SW==2, simple 2-deep
        LOADA(0, kwv);      LOADB(0, kwv);
        LOADA(1, kwv + KT); LOADB(1, kwv + KT);
        { MKFRAGS(0, A0); mfma_all(A0, bq0); }
        { MKFRAGS(1, A1); mfma_all(A1, bq1); }
    }

    // ---- k-half reduction: ONE barrier ----
    const int rbase = jg * 64 * LRP;
    if (kh == 1) {
#pragma unroll
        for (int g = 0; g < NG; ++g)
#pragma unroll
            for (int j2 = 0; j2 < NJW; ++j2)
#pragma unroll
                for (int r = 0; r < 4; ++r)
                    R[rbase + (g * 16 + quad * 4 + r) * LRP + j2 * 16 + l15] = acc[g * NJW + j2][r];
    }
    __syncthreads();
    if (kh != 0) return;
#pragma unroll
    for (int g = 0; g < NG; ++g)
#pragma unroll
        for (int j2 = 0; j2 < NJW; ++j2)
#pragma unroll
            for (int r = 0; r < 4; ++r)
                acc[g * NJW + j2][r] += R[rbase + (g * 16 + quad * 4 + r) * LRP + j2 * 16 + l15];

    // ---- epilogue (waves 0 and 2: disjoint col-halves) ----
    float mul[NG][4];
    if constexpr (MODE != 0) {
#pragma unroll
        for (int g = 0; g < NG; ++g) {
            const float4 rv = *(const float4*)&rcp[(size_t)batch * RL + m0 + g * 16 + quad * 4];
            mul[g][0] = rv.x; mul[g][1] = rv.y; mul[g][2] = rv.z; mul[g][3] = rv.w;
        }
    }
#pragma unroll
    for (int g = 0; g < NG; ++g) {
        const int row = m0 + g * 16 + quad * 4;
        if constexpr (MODE == 2) {
            float* op = outF + ((size_t)batch * N_ + row) * C_;
#pragma unroll
            for (int j2 = 0; j2 < NJW; ++j2) {
                const int c = (jw + j2) * 16 + l15;
#pragma unroll
                for (int r = 0; r < 4; ++r) op[(size_t)r * C_ + c] = acc[g * NJW + j2][r] * mul[g][r];
            }
        } else {
#pragma unroll
            for (int j2 = 0; j2 < NJW; ++j2) {
                const int c = (jw + j2) * 16 + l15;
                float v0, v1, v2, v3;
                if constexpr (MODE == 0) {
                    float bb = bias[c];
                    v0 = acc[g * NJW + j2][0] + bb; v1 = acc[g * NJW + j2][1] + bb;
                    v2 = acc[g * NJW + j2][2] + bb; v3 = acc[g * NJW + j2][3] + bb;
                } else {
                    v0 = acc[g * NJW + j2][0] * mul[g][0]; v1 = acc[g * NJW + j2][1] * mul[g][1];
                    v2 = acc[g * NJW + j2][2] * mul[g][2]; v3 = acc[g * NJW + j2][3] * mul[g][3];
                }
                uint32_t q0 = (uint32_t)bf16_rne(v0) | ((uint32_t)bf16_rne(v1) << 16);
                uint32_t q1 = (uint32_t)bf16_rne(v2) | ((uint32_t)bf16_rne(v3) << 16);
                uint16_t* op = outT + ((size_t)batch * C_ + c) * OLD + row;
                *(uint2*)op = make_uint2(q0, q1);
            }
        }
    }
}

// Named wrappers -> attributable rocprof rows
__global__ __launch_bounds__(256, 2)
void fc_k(const float* __restrict__ Ax, const uint16_t* __restrict__ Btb,
          const float* __restrict__ bias, uint16_t* __restrict__ outT) {
    gemm_body<0>(Ax, nullptr, Btb, bias, nullptr, outT, nullptr);
}
__global__ __launch_bounds__(256, 2)
void v2e_k(const uint32_t* __restrict__ HT, const uint16_t* __restrict__ Btb,
           const float* __restrict__ rcp, uint16_t* __restrict__ outT) {
    gemm_body<1>(nullptr, HT, Btb, nullptr, rcp, outT, nullptr);
}
__global__ __launch_bounds__(256, 2)
void e2v_k(const uint32_t* __restrict__ HTe, const uint16_t* __restrict__ Btb,
           const float* __restrict__ rcp, float* __restrict__ outF) {
    gemm_body<2>(nullptr, HTe, Btb, nullptr, rcp, nullptr, outF);
}

// ---------------------------------------------------------------------------
extern "C" void kernel_launch(void* const* d_in, const int* in_sizes, int n_in,
                              void* d_out, int out_size, void* d_ws, size_t ws_size,
                              hipStream_t stream) {
    const float* x    = (const float*)d_in[0];   // [8,4096,128]
    const float* H    = (const float*)d_in[1];   // [8,4096,2048]
    const float* W    = (const float*)d_in[2];   // [128,128]
    const float* bias = (const float*)d_in[3];   // [128]
    float* out = (float*)d_out;                  // [8,4096,128]

    // ws (~20.3 MB): HT 8MB | HTe 8MB | WTb 32KB | ebfT 4MB | rs_e 64KB | rd_n 128KB
    uint32_t* HT   = (uint32_t*)d_ws;
    uint32_t* HTe  = HT + HT_E;
    uint16_t* WTb  = (uint16_t*)(HTe + HT_E);
    uint16_t* ebfT = WTb + WT_E;
    float*    rs_e = (float*)(ebfT + EBF_E);
    float*    rd_n = rs_e + RS_E;
    uint16_t* xwbT = (uint16_t*)d_out;           // d_out is dead scratch until e2v

    pack_kernel<<<dim3(8192), dim3(256), 0, stream>>>(H, HT, HTe);
    prep_kernel<<<dim3(256), dim3(256), 0, stream>>>(W, HT, HTe, WTb, rs_e, rd_n);
    fc_k <<<dim3(8 * (N_ / MT)), dim3(256), 0, stream>>>(x, WTb, bias, xwbT);
    v2e_k<<<dim3(8 * (E_ / MT)), dim3(256), 0, stream>>>(HT, xwbT, rs_e, ebfT);
    e2v_k<<<dim3(8 * (N_ / MT)), dim3(256), 0, stream>>>(HTe, ebfT, rd_n, out);
}